// Round 18
// baseline (1937.590 us; speedup 1.0000x reference)
//
#include <hip/hip_runtime.h>
#include <math.h>
#include <limits.h>

#define RPB 64     // x-rows per block
#define CCH 64     // train cols per chunk
#define KF  64     // f per K-chunk (4 chunks cover F=256) -> 35KB LDS, 4 blk/CU
#define NSPL 16    // N-splits (grid = 32 rowblk x 16 = 512 blocks)
#define PAD 66     // LDS row stride in floats (even -> 8B-aligned float2)

typedef float f32x2 __attribute__((ext_vector_type(2)));

// lexicographic (distance, index) compare == jax.lax.top_k stable tie-break
__device__ __forceinline__ bool plt(float da, int ia, float db, int ib) {
    return (da < db) || ((da == db) && (ia < ib));
}

// branchless insert of candidate (d,n) into sorted ascending top-3
__device__ __forceinline__ void insert3(float d, int n, float td[3], int ti[3]) {
    bool b = plt(d, n, td[2], ti[2]);
    float d2 = b ? d : td[2];  int i2 = b ? n : ti[2];
    bool c = plt(d2, i2, td[1], ti[1]);
    float nd1 = c ? d2 : td[1];    int ni1 = c ? i2 : ti[1];
    float nd2 = c ? td[1] : d2;    int ni2 = c ? ti[1] : i2;
    bool e = plt(nd1, ni1, td[0], ti[0]);
    float od0 = td[0]; int oi0 = ti[0];
    td[0] = e ? nd1 : od0;  ti[0] = e ? ni1 : oi0;
    td[1] = e ? od0 : nd1;  ti[1] = e ? oi0 : ni1;
    td[2] = nd2;            ti[2] = ni2;
}

// merge two sorted top-3 lists (b into a), branchless
__device__ __forceinline__ void merge3(float ad[3], int ai[3],
                                       const float bd[3], const int bi[3]) {
    bool b0 = plt(ad[0], ai[0], bd[0], bi[0]);
    float c0d = b0 ? ad[0] : bd[0];  int c0i = b0 ? ai[0] : bi[0];
    float w0d = b0 ? bd[0] : ad[0];  int w0i = b0 ? bi[0] : ai[0];
    bool b1 = plt(ad[1], ai[1], bd[1], bi[1]);
    float m1d = b1 ? ad[1] : bd[1];  int m1i = b1 ? ai[1] : bi[1];
    float M1d = b1 ? bd[1] : ad[1];  int M1i = b1 ? bi[1] : ai[1];
    bool br1 = plt(w0d, w0i, m1d, m1i);
    float r1d = br1 ? w0d : m1d;     int r1i = br1 ? w0i : m1i;
    float t1d = br1 ? m1d : w0d;     int t1i = br1 ? m1i : w0i; // max(w0,m1)
    bool b2 = plt(ad[2], ai[2], bd[2], bi[2]);
    float t2d = b2 ? ad[2] : bd[2];  int t2i = b2 ? ai[2] : bi[2]; // min(a2,b2)
    bool c1 = plt(M1d, M1i, t1d, t1i);
    float ud = c1 ? M1d : t1d;       int ui = c1 ? M1i : t1i;
    bool c2 = plt(ud, ui, t2d, t2i);
    float r2d = c2 ? ud : t2d;       int r2i = c2 ? ui : t2i;
    ad[0] = c0d; ai[0] = c0i;
    ad[1] = r1d; ai[1] = r1i;
    ad[2] = r2d; ai[2] = r2i;
}

// x-row norms only (wave per row) -> ln.  (R13-proven structure)
__global__ __launch_bounds__(256)
void xnorm_all(const float* __restrict__ x, float* __restrict__ ln,
               int F, int B) {
    int wid  = (blockIdx.x * 256 + threadIdx.x) >> 6;
    int lane = threadIdx.x & 63;
    if (wid >= B) return;
    float s = 0.f;
    #pragma unroll
    for (int k = 0; k < 4; ++k) {
        float v = x[(size_t)wid * F + lane + 64 * k];
        s = fmaf(v, v, s);
    }
    s += __shfl_xor(s, 1);
    s += __shfl_xor(s, 2);
    s += __shfl_xor(s, 4);
    s += __shfl_xor(s, 8);
    s += __shfl_xor(s, 16);
    s += __shfl_xor(s, 32);
    if (lane == 0) ln[wid] = s;
}

// 4x4 micro-tiled distance + top-3; KF=64 K-chunks -> 35KB LDS ->
// 4 blocks/CU (4 waves/SIMD: latency/barrier stalls overlap).
// Inner loop = R17-proven packed f32x2 FMA.
__global__ __launch_bounds__(256)
void knn_split4(const float* __restrict__ x, const float* __restrict__ t,
                const float* __restrict__ feat, const float* __restrict__ ln,
                float* __restrict__ outbuf, int F, int N, int B) {
    __shared__ float xs[RPB * PAD];    // 16.9 KB
    __shared__ float ts_[CCH * PAD];   // 16.9 KB
    __shared__ float fs[256];
    __shared__ float rsum[CCH];

    const int tid = threadIdx.x;
    const int colt = tid & 15;
    const int rowg = tid >> 4;
    const int rowblk = blockIdx.x & 31;          // B/RPB == 32
    const int split  = blockIdx.x >> 5;          // 0..15
    const int row0 = rowblk * RPB;
    const int nslice = N / NSPL;                 // 4096
    const int nbase = split * nslice;

    fs[tid] = feat[tid];               // F == 256 (visible after first barrier)

    const float lvA = ln[row0 + rowg];
    const float lvB = ln[row0 + rowg + 16];
    const float lvC = ln[row0 + rowg + 32];
    const float lvD = ln[row0 + rowg + 48];

    float tdA[3], tdB[3], tdC[3], tdD[3];
    int   tiA[3], tiB[3], tiC[3], tiD[3];
    tdA[0]=tdA[1]=tdA[2]=INFINITY; tiA[0]=tiA[1]=tiA[2]=INT_MAX;
    tdB[0]=tdB[1]=tdB[2]=INFINITY; tiB[0]=tiB[1]=tiB[2]=INT_MAX;
    tdC[0]=tdC[1]=tdC[2]=INFINITY; tiC[0]=tiC[1]=tiC[2]=INT_MAX;
    tdD[0]=tdD[1]=tdD[2]=INFINITY; tiD[0]=tiD[1]=tiD[2]=INT_MAX;

    #pragma unroll 1
    for (int cb = 0; cb < nslice; cb += CCH) {   // 64 col-chunks
        const int n0 = nbase + cb;
        // packed pairwise accumulators (even-f / odd-f partial sums)
        f32x2 v00 = {0.f, 0.f}, v01 = {0.f, 0.f}, v02 = {0.f, 0.f}, v03 = {0.f, 0.f};
        f32x2 v10 = {0.f, 0.f}, v11 = {0.f, 0.f}, v12 = {0.f, 0.f}, v13 = {0.f, 0.f};
        f32x2 v20 = {0.f, 0.f}, v21 = {0.f, 0.f}, v22 = {0.f, 0.f}, v23 = {0.f, 0.f};
        f32x2 v30 = {0.f, 0.f}, v31 = {0.f, 0.f}, v32 = {0.f, 0.f}, v33 = {0.f, 0.f};

        #pragma unroll 1
        for (int kc = 0; kc < 4; ++kc) {         // 4 K-chunks of 64 f
            const int f0 = kc * KF;
            // stage 64 rows x 64 f of x and t (coalesced: f = tid&63)
            {
                const int fr = tid & 63;
                const int r4 = tid >> 6;         // 0..3
                #pragma unroll 4
                for (int q = 0; q < 16; ++q) {
                    int row = q * 4 + r4;
                    xs[row * PAD + fr] = x[(size_t)(row0 + row) * F + f0 + fr];
                    ts_[row * PAD + fr] = t[(size_t)(n0 + row) * F + f0 + fr];
                }
            }
            __syncthreads();

            // cooperative feat-weighted col norms: 4 threads per col
            {
                const int c = tid >> 2;          // 0..63
                const int g = tid & 3;
                float s = 0.f;
                #pragma unroll 8
                for (int k = 0; k < 16; ++k) {
                    int f = g + 4 * k;
                    float v = ts_[c * PAD + f] * fs[f0 + f];
                    s = fmaf(v, v, s);
                }
                s += __shfl_xor(s, 1);
                s += __shfl_xor(s, 2);
                if (g == 0) { if (kc == 0) rsum[c] = s; else rsum[c] += s; }
            }

            // 4x4 dot over this K-chunk: 8 ds_read_b64 -> 16 v_pk_fma_f32
            #pragma unroll 4
            for (int f = 0; f < KF; f += 2) {
                f32x2 t0 = *(const f32x2*)&ts_[colt * PAD + f];
                f32x2 t1 = *(const f32x2*)&ts_[(colt + 16) * PAD + f];
                f32x2 t2 = *(const f32x2*)&ts_[(colt + 32) * PAD + f];
                f32x2 t3 = *(const f32x2*)&ts_[(colt + 48) * PAD + f];
                f32x2 x0 = *(const f32x2*)&xs[rowg * PAD + f];
                f32x2 x1 = *(const f32x2*)&xs[(rowg + 16) * PAD + f];
                f32x2 x2 = *(const f32x2*)&xs[(rowg + 32) * PAD + f];
                f32x2 x3 = *(const f32x2*)&xs[(rowg + 48) * PAD + f];
                v00 = __builtin_elementwise_fma(x0, t0, v00);
                v01 = __builtin_elementwise_fma(x0, t1, v01);
                v02 = __builtin_elementwise_fma(x0, t2, v02);
                v03 = __builtin_elementwise_fma(x0, t3, v03);
                v10 = __builtin_elementwise_fma(x1, t0, v10);
                v11 = __builtin_elementwise_fma(x1, t1, v11);
                v12 = __builtin_elementwise_fma(x1, t2, v12);
                v13 = __builtin_elementwise_fma(x1, t3, v13);
                v20 = __builtin_elementwise_fma(x2, t0, v20);
                v21 = __builtin_elementwise_fma(x2, t1, v21);
                v22 = __builtin_elementwise_fma(x2, t2, v22);
                v23 = __builtin_elementwise_fma(x2, t3, v23);
                v30 = __builtin_elementwise_fma(x3, t0, v30);
                v31 = __builtin_elementwise_fma(x3, t1, v31);
                v32 = __builtin_elementwise_fma(x3, t2, v32);
                v33 = __builtin_elementwise_fma(x3, t3, v33);
            }
            __syncthreads();   // before next K-chunk restages xs/ts_
        }

        // fold packed partials, then distances + running top-3
        const float a00 = v00[0] + v00[1], a01 = v01[0] + v01[1];
        const float a02 = v02[0] + v02[1], a03 = v03[0] + v03[1];
        const float a10 = v10[0] + v10[1], a11 = v11[0] + v11[1];
        const float a12 = v12[0] + v12[1], a13 = v13[0] + v13[1];
        const float a20 = v20[0] + v20[1], a21 = v21[0] + v21[1];
        const float a22 = v22[0] + v22[1], a23 = v23[0] + v23[1];
        const float a30 = v30[0] + v30[1], a31 = v31[0] + v31[1];
        const float a32 = v32[0] + v32[1], a33 = v33[0] + v33[1];

        const float rv0 = rsum[colt];
        const float rv1 = rsum[colt + 16];
        const float rv2 = rsum[colt + 32];
        const float rv3 = rsum[colt + 48];
        const int nc0 = n0 + colt, nc1 = n0 + colt + 16,
                  nc2 = n0 + colt + 32, nc3 = n0 + colt + 48;
        insert3(sqrtf(lvA + rv0) - 2.0f * a00, nc0, tdA, tiA);
        insert3(sqrtf(lvA + rv1) - 2.0f * a01, nc1, tdA, tiA);
        insert3(sqrtf(lvA + rv2) - 2.0f * a02, nc2, tdA, tiA);
        insert3(sqrtf(lvA + rv3) - 2.0f * a03, nc3, tdA, tiA);
        insert3(sqrtf(lvB + rv0) - 2.0f * a10, nc0, tdB, tiB);
        insert3(sqrtf(lvB + rv1) - 2.0f * a11, nc1, tdB, tiB);
        insert3(sqrtf(lvB + rv2) - 2.0f * a12, nc2, tdB, tiB);
        insert3(sqrtf(lvB + rv3) - 2.0f * a13, nc3, tdB, tiB);
        insert3(sqrtf(lvC + rv0) - 2.0f * a20, nc0, tdC, tiC);
        insert3(sqrtf(lvC + rv1) - 2.0f * a21, nc1, tdC, tiC);
        insert3(sqrtf(lvC + rv2) - 2.0f * a22, nc2, tdC, tiC);
        insert3(sqrtf(lvC + rv3) - 2.0f * a23, nc3, tdC, tiC);
        insert3(sqrtf(lvD + rv0) - 2.0f * a30, nc0, tdD, tiD);
        insert3(sqrtf(lvD + rv1) - 2.0f * a31, nc1, tdD, tiD);
        insert3(sqrtf(lvD + rv2) - 2.0f * a32, nc2, tdD, tiD);
        insert3(sqrtf(lvD + rv3) - 2.0f * a33, nc3, tdD, tiD);
        __syncthreads();   // rsum/ts_ reused next chunk
    }

    // merge across the 16 colt threads sharing a row-group (16-aligned lanes)
    #pragma unroll 1
    for (int m = 1; m < 16; m <<= 1) {
        float od[3]; int oi[3];
        #pragma unroll
        for (int s = 0; s < 3; ++s) { od[s] = __shfl_xor(tdA[s], m); oi[s] = __shfl_xor(tiA[s], m); }
        merge3(tdA, tiA, od, oi);
        #pragma unroll
        for (int s = 0; s < 3; ++s) { od[s] = __shfl_xor(tdB[s], m); oi[s] = __shfl_xor(tiB[s], m); }
        merge3(tdB, tiB, od, oi);
        #pragma unroll
        for (int s = 0; s < 3; ++s) { od[s] = __shfl_xor(tdC[s], m); oi[s] = __shfl_xor(tiC[s], m); }
        merge3(tdC, tiC, od, oi);
        #pragma unroll
        for (int s = 0; s < 3; ++s) { od[s] = __shfl_xor(tdD[s], m); oi[s] = __shfl_xor(tiD[s], m); }
        merge3(tdD, tiD, od, oi);
    }
    if (colt == 0) {
        int baseA = ((row0 + rowg)      * NSPL + split) * 6;
        int baseB = ((row0 + rowg + 16) * NSPL + split) * 6;
        int baseC = ((row0 + rowg + 32) * NSPL + split) * 6;
        int baseD = ((row0 + rowg + 48) * NSPL + split) * 6;
        #pragma unroll
        for (int s = 0; s < 3; ++s) {
            outbuf[baseA + s] = tdA[s];  outbuf[baseA + 3 + s] = (float)tiA[s];
            outbuf[baseB + s] = tdB[s];  outbuf[baseB + 3 + s] = (float)tiB[s];
            outbuf[baseC + s] = tdC[s];  outbuf[baseC + 3 + s] = (float)tiC[s];
            outbuf[baseD + s] = tdD[s];  outbuf[baseD + 3 + s] = (float)tiD[s];
        }
    }
}

// Merge NSPL=16 candidate triples per row -> top-3 -> labels -> stash.
// 256 thr = 16 rows x 16 lanes.
__global__ __launch_bounds__(256)
void knn_merge(float* __restrict__ buf, const int* __restrict__ labels,
               int B, int N, int stashBase) {
    const int tid = threadIdx.x;
    const int row = blockIdx.x * 16 + (tid >> 4);
    const int j = tid & 15;
    const int base = (row * NSPL + j) * 6;
    float d[3]; int ii[3];
    #pragma unroll
    for (int s = 0; s < 3; ++s) {
        d[s] = buf[base + s];
        ii[s] = (int)buf[base + 3 + s];
    }
    #pragma unroll
    for (int m = 1; m < 16; m <<= 1) {
        float od[3]; int oi[3];
        #pragma unroll
        for (int s = 0; s < 3; ++s) { od[s] = __shfl_xor(d[s], m); oi[s] = __shfl_xor(ii[s], m); }
        merge3(d, ii, od, oi);
    }
    if (j == 0) {
        #pragma unroll
        for (int s = 0; s < 3; ++s) {
            int idx = ii[s];
            idx = idx < 0 ? 0 : (idx >= N ? N - 1 : idx);   // never fault
            buf[stashBase + row * 3 + s] = (float)labels[idx];
        }
    }
}

// one-hot rows [0, rowsMain): reads stash, never writes it.  (proven)
__global__ void out_main(float* __restrict__ out, int B, int L,
                         int stashBase, int rowsMain) {
    int tid = blockIdx.x * blockDim.x + threadIdx.x;
    if (tid >= rowsMain * L) return;
    int i = tid / L, c = tid - i * L;
    int s = (int)out[stashBase + i] + (int)out[stashBase + B + i]
          + (int)out[stashBase + 2 * B + i];
    out[tid] = (c == s / 3) ? 1.0f : 0.0f;
}

// single block: buffers needed stash into LDS, barriers, overwrites tail. (proven)
__global__ __launch_bounds__(256)
void out_tail(float* __restrict__ out, int B, int L,
              int stashBase, int rowsMain) {
    __shared__ int l0[128], l1[128], l2[128];
    int nt = B - rowsMain;
    for (int q = threadIdx.x; q < nt * 3; q += 256) {
        int j = q / nt, i = q - j * nt;
        int v = (int)out[stashBase + j * B + rowsMain + i];
        if (j == 0) l0[i] = v; else if (j == 1) l1[i] = v; else l2[i] = v;
    }
    __syncthreads();
    int base = rowsMain * L;
    for (int e = threadIdx.x; e < B * L - base; e += 256) {
        int rr = (base + e) / L - rowsMain, c = (base + e) % L;
        int s = l0[rr] + l1[rr] + l2[rr];
        out[base + e] = (c == s / 3) ? 1.0f : 0.0f;
    }
}

extern "C" void kernel_launch(void* const* d_in, const int* in_sizes, int n_in,
                              void* d_out, int out_size, void* d_ws, size_t ws_size,
                              hipStream_t stream) {
    const float* x      = (const float*)d_in[0];
    const float* t      = (const float*)d_in[1];
    const float* feat   = (const float*)d_in[2];
    const int*   labels = (const int*)d_in[3];
    float*       out    = (float*)d_out;
    const int F = in_sizes[2];           // 256
    const int B = in_sizes[0] / F;       // 2048
    const int N = in_sizes[3];           // 65536
    const int L = out_size / B;          // 100

    const int stashBase = out_size - 3 * B;   // 198656
    const int rowsMain  = stashBase / L;      // 1986
    // scratch layout in d_out (floats):
    //   cand  [0, 196608) = B*NSPL*6 ; ln [196608, 198656) ; stash [198656, 204800)
    float* cand = out;
    float* ln   = out + (size_t)B * NSPL * 6;  // 196608

    xnorm_all<<<(B * 64 + 255) / 256, 256, 0, stream>>>(x, ln, F, B);

    const int nblk = (B / RPB) * NSPL;        // 512 (4 blocks/CU)
    knn_split4<<<nblk, 256, 0, stream>>>(x, t, feat, ln, cand, F, N, B);
    knn_merge<<<B / 16, 256, 0, stream>>>(out, labels, B, N, stashBase);
    out_main<<<(rowsMain * L + 255) / 256, 256, 0, stream>>>(
        out, B, L, stashBase, rowsMain);
    out_tail<<<1, 256, 0, stream>>>(out, B, L, stashBase, rowsMain);
}